// Round 5
// baseline (2629.295 us; speedup 1.0000x reference)
//
#include <hip/hip_runtime.h>

#define WD   192
#define HD   192
#define HWD  (WD*HD)
#define NCH  64
#define NOUT 64
#define NK   5
#define BAND 6             // rows per block
#define SLOTS 3            // ring slots (rows): r-1, r, r+1; write r+2 over r-1
#define COLS 194           // 1 zero-pad + 192 + 1 zero-pad
#define ROWB 128           // bytes per pixel entry (64 ch bf16), XOR-swizzled

typedef __attribute__((ext_vector_type(8))) short short8;
typedef __attribute__((ext_vector_type(4))) float f32x4;

__device__ inline ushort f2bf(float f) {
  union { float f; unsigned u; } xx; xx.f = f;
  unsigned u = xx.u;
  return (ushort)((u + 0x7FFFu + ((u >> 16) & 1u)) >> 16);   // RNE
}

// Swizzled LDS byte offset: row-stride 128 B, XOR (pix&7) into bits 4..6.
// Involution applied on BOTH write and read -> bijective, conflict-free b128.
// NOTE: cbyte < 128; XOR stays inside the row. Callers must apply the swizzle
// per cbyte value (addr is NOT linear in cbyte across bits 4..6).
__device__ inline int ldso(int slot, int pix, int cbyte) {
  int byte = (slot * COLS + pix) * ROWB + cbyte;
  return byte ^ ((pix & 7) << 4);
}

// taps[5..9] = dr ; taps[10..14] = dc   (runtime rot read on-device)
__global__ void prep_taps_k(const int* __restrict__ rot, int* __restrict__ taps) {
  const int ring_r[8] = {0,0,1,2,2,2,1,0};
  const int ring_c[8] = {1,2,2,2,1,0,0,0};
  int off = ((rot[0] % 8) + 8) % 8;   // step = 8/kernel_rot = 1
  for (int k = 0; k < 4; ++k) {
    int p = (2*k + off) & 7;
    taps[k] = 0; taps[5 + k] = ring_r[p] - 1; taps[10 + k] = ring_c[p] - 1;
  }
  taps[4] = 0; taps[9] = 0; taps[14] = 0;   // center tap
}

__device__ inline unsigned s3(int gr) { return (unsigned)(gr + 3) % 3u; }

__global__ __launch_bounds__(512, 4) void rconv_ring_k(
    const float* __restrict__ x, const float* __restrict__ w,
    const int* __restrict__ taps, float* __restrict__ out) {
  __shared__ ushort lds[SLOTS * COLS * (ROWB / 2)];   // 74,496 B -> 2 blocks/CU
  char* ldsb = (char*)lds;

  const int tid  = threadIdx.x;
  const int lane = tid & 63;
  const int wv   = tid >> 6;        // 0..7
  const int l15  = lane & 15;
  const int g    = lane >> 4;       // 0..3
  const int r0   = blockIdx.x * BAND;
  const int n    = blockIdx.y;
  const int o0w  = (wv & 1) * 32;   // o-half owned by this wave
  const int wq   = wv >> 1;         // pixel quarter (48 pix)

  int dr[NK], dc[NK];
  #pragma unroll
  for (int k = 0; k < NK; ++k) { dr[k] = taps[5 + k]; dc[k] = taps[10 + k]; }

  // A fragments: W[o0w+ot*16+l15][kc*32+g*8+j][k]  (same (g,j)->k map as B)
  short8 a[2][2][NK];
  #pragma unroll
  for (int ot = 0; ot < 2; ++ot)
    #pragma unroll
    for (int kc = 0; kc < 2; ++kc)
      #pragma unroll
      for (int k = 0; k < NK; ++k) {
        short8 t;
        #pragma unroll
        for (int j = 0; j < 8; ++j)
          t[j] = (short)f2bf(w[(size_t)(o0w + ot*16 + l15) * (NCH*NK)
                               + (kc*32 + g*8 + j) * NK + k]);
        a[ot][kc][k] = t;
      }

  // staging: wave wv owns channels [wv*8, wv*8+8)
  const float* xn = x + ((size_t)n * NCH + wv * 8) * HWD;

  auto stage_load = [&](int gr, float v[3][8]) {
    bool vr = (gr >= 0) && (gr < HD);
    if (vr) {
      const float* xr = xn + (size_t)gr * WD;
      #pragma unroll
      for (int i = 0; i < 3; ++i)
        #pragma unroll
        for (int j = 0; j < 8; ++j)
          v[i][j] = xr[(size_t)j * HWD + i * 64 + lane];
    } else {
      #pragma unroll
      for (int i = 0; i < 3; ++i)
        #pragma unroll
        for (int j = 0; j < 8; ++j) v[i][j] = 0.f;
    }
  };
  auto stage_write = [&](int gr, const float v[3][8]) {
    int s = s3(gr);
    #pragma unroll
    for (int i = 0; i < 3; ++i) {
      short8 t;
      #pragma unroll
      for (int j = 0; j < 8; ++j) t[j] = (short)f2bf(v[i][j]);
      *reinterpret_cast<short8*>(ldsb + ldso(s, 1 + i * 64 + lane, wv * 16)) = t;
    }
    if (lane < 2) {   // zero the left/right pad pixels (cols 0 and 193)
      short8 z = (short8){0,0,0,0,0,0,0,0};
      *reinterpret_cast<short8*>(ldsb + ldso(s, lane * (COLS - 1), wv * 16)) = z;
    }
  };

  // prologue: rows r0-1, r0, r0+1 into slots s3(r0-1), s3(r0), s3(r0+1)
  {
    float v[3][8];
    stage_load(r0 - 1, v); stage_write(r0 - 1, v);
    stage_load(r0,     v); stage_write(r0,     v);
    stage_load(r0 + 1, v); stage_write(r0 + 1, v);
  }
  __syncthreads();

  for (int r = r0; r < r0 + BAND; ++r) {
    // 1. issue next-row staging loads early (hide HBM latency under MFMA)
    float v[3][8];
    const bool do_stage = (r + 2 <= r0 + BAND);
    if (do_stage) stage_load(r + 2, v);

    // 2. compute row r from slots (r-1, r, r+1).
    //    Two swizzled byte offsets per tap: channels [g*8..) and [32+g*8..).
    //    (b1 is NOT bp0+64: the XOR swizzle flips bit 6 when pix&4.)
    int bo0[NK], bo1[NK];
    #pragma unroll
    for (int k = 0; k < NK; ++k) {
      int pix = wq * 48 + dc[k] + 1 + l15;
      bo0[k] = ldso(s3(r + dr[k]), pix, g * 16);
      bo1[k] = ldso(s3(r + dr[k]), pix, g * 16 + 64);
    }

    f32x4 acc[3][2];
    #pragma unroll
    for (int t = 0; t < 3; ++t) {
      acc[t][0] = (f32x4){0.f, 0.f, 0.f, 0.f};
      acc[t][1] = (f32x4){0.f, 0.f, 0.f, 0.f};
    }

    __builtin_amdgcn_s_setprio(1);
    #pragma unroll
    for (int t = 0; t < 3; ++t)
      #pragma unroll
      for (int k = 0; k < NK; ++k) {
        // pixel advance by 16: (pix+16)&7 == pix&7 and +16*128 only touches
        // bits >= 11 -> linear add is swizzle-safe.
        short8 b0 = *reinterpret_cast<const short8*>(ldsb + bo0[k] + t * 16 * ROWB);
        short8 b1 = *reinterpret_cast<const short8*>(ldsb + bo1[k] + t * 16 * ROWB);
        acc[t][0] = __builtin_amdgcn_mfma_f32_16x16x32_bf16(a[0][0][k], b0, acc[t][0], 0, 0, 0);
        acc[t][1] = __builtin_amdgcn_mfma_f32_16x16x32_bf16(a[1][0][k], b0, acc[t][1], 0, 0, 0);
        acc[t][0] = __builtin_amdgcn_mfma_f32_16x16x32_bf16(a[0][1][k], b1, acc[t][0], 0, 0, 0);
        acc[t][1] = __builtin_amdgcn_mfma_f32_16x16x32_bf16(a[1][1][k], b1, acc[t][1], 0, 0, 0);
      }
    __builtin_amdgcn_s_setprio(0);

    // 3. all waves done reading slot (r-1)%3 -> safe to overwrite with row r+2
    __syncthreads();
    if (do_stage) stage_write(r + 2, v);
    __syncthreads();

    // 4. deferred store of row r (drains under next step's loads + MFMA)
    size_t ob = ((size_t)(n * NOUT + o0w + 4 * g) * HD + r) * WD + wq * 48 + l15;
    #pragma unroll
    for (int t = 0; t < 3; ++t)
      #pragma unroll
      for (int ot = 0; ot < 2; ++ot)
        #pragma unroll
        for (int q = 0; q < 4; ++q)
          out[ob + (size_t)(ot * 16 + q) * HWD + t * 16] = acc[t][ot][q];
  }
}

extern "C" void kernel_launch(void* const* d_in, const int* in_sizes, int n_in,
                              void* d_out, int out_size, void* d_ws, size_t ws_size,
                              hipStream_t stream) {
  const float* x = (const float*)d_in[0];
  const float* w = (const float*)d_in[1];
  const int* rot = (const int*)d_in[2];
  float* out     = (float*)d_out;
  int* taps      = (int*)d_ws;

  const int nbatch = in_sizes[0] / (NCH * HWD);   // 16

  hipLaunchKernelGGL(prep_taps_k, dim3(1), dim3(1), 0, stream, rot, taps);
  hipLaunchKernelGGL(rconv_ring_k, dim3(HD / BAND, nbatch), dim3(512), 0, stream,
                     x, w, taps, out);
}

// Round 6
// 78.300 us; speedup vs baseline: 33.5796x; 33.5796x over previous
//
#include <hip/hip_runtime.h>

#define WD   192
#define HD   192
#define HWD  (WD*HD)
#define NCH  64
#define NOUT 64
#define NK   5
#define BAND 12            // rows per block; grid = 16 bands x 16 imgs = 256 = 1/CU
#define COLS 194           // 1 zero-pad + 192 + 1 zero-pad
#define ROWB 128           // bytes per pixel entry (64 ch bf16), XOR-swizzled

typedef __attribute__((ext_vector_type(8))) short short8;
typedef __attribute__((ext_vector_type(4))) float f32x4;

__device__ inline ushort f2bf(float f) {
  union { float f; unsigned u; } xx; xx.f = f;
  unsigned u = xx.u;
  return (ushort)((u + 0x7FFFu + ((u >> 16) & 1u)) >> 16);   // RNE
}

// Swizzled LDS byte offset: row-stride 128 B, XOR (pix&7) into bits 4..6.
// Involution on BOTH write and read -> bijective, conflict-free b128.
// NOT linear in cbyte across bits 4..6 -> compute per cbyte value.
__device__ inline int ldso(int slot, int pix, int cbyte) {
  int byte = (slot * COLS + pix) * ROWB + cbyte;
  return byte ^ ((pix & 7) << 4);
}

// taps[5..9] = dr ; taps[10..14] = dc   (runtime rot read on-device)
__global__ void prep_taps_k(const int* __restrict__ rot, int* __restrict__ taps) {
  const int ring_r[8] = {0,0,1,2,2,2,1,0};
  const int ring_c[8] = {1,2,2,2,1,0,0,0};
  int off = ((rot[0] % 8) + 8) % 8;   // step = 8/kernel_rot = 1
  for (int k = 0; k < 4; ++k) {
    int p = (2*k + off) & 7;
    taps[k] = 0; taps[5 + k] = ring_r[p] - 1; taps[10 + k] = ring_c[p] - 1;
  }
  taps[4] = 0; taps[9] = 0; taps[14] = 0;   // center tap
}

// Raw barrier WITHOUT the __syncthreads vmcnt(0) drain: only LDS ops fenced.
// Prefetch loads and output stores stay in flight across it (T3/T4 pattern).
__device__ inline void lds_barrier() {
  __builtin_amdgcn_sched_barrier(0);
  asm volatile("s_waitcnt lgkmcnt(0)" ::: "memory");
  __builtin_amdgcn_sched_barrier(0);
  __builtin_amdgcn_s_barrier();
  __builtin_amdgcn_sched_barrier(0);
}

__global__ __launch_bounds__(512, 2) void rconv_ring_k(
    const float* __restrict__ x, const float* __restrict__ w,
    const int* __restrict__ taps, float* __restrict__ out) {
  __shared__ ushort lds[4 * COLS * (ROWB / 2)];   // 99,328 B -> 1 block/CU
  char* ldsb = (char*)lds;

  const int tid  = threadIdx.x;
  const int lane = tid & 63;
  const int wv   = tid >> 6;        // 0..7
  const int l15  = lane & 15;
  const int g    = lane >> 4;       // 0..3
  const int r0   = blockIdx.x * BAND;
  const int n    = blockIdx.y;
  const int o0w  = (wv & 1) * 32;   // o-half owned by this wave
  const int wq   = wv >> 1;         // pixel quarter (48 pix)

  int dr[NK], dc[NK];
  #pragma unroll
  for (int k = 0; k < NK; ++k) { dr[k] = taps[5 + k]; dc[k] = taps[10 + k]; }

  // A fragments: W[o0w+ot*16+l15][kc*32+g*8+j][k]  (same (g,j)->k map as B)
  short8 a[2][2][NK];
  #pragma unroll
  for (int ot = 0; ot < 2; ++ot)
    #pragma unroll
    for (int kc = 0; kc < 2; ++kc)
      #pragma unroll
      for (int k = 0; k < NK; ++k) {
        short8 t;
        #pragma unroll
        for (int j = 0; j < 8; ++j)
          t[j] = (short)f2bf(w[(size_t)(o0w + ot*16 + l15) * (NCH*NK)
                               + (kc*32 + g*8 + j) * NK + k]);
        a[ot][kc][k] = t;
      }

  // staging: wave wv owns channels [wv*8, wv*8+8)
  const float* xn = x + ((size_t)n * NCH + wv * 8) * HWD;

  auto stage_load = [&](int gr, float v[3][8]) {
    bool vr = (gr >= 0) && (gr < HD);
    if (vr) {
      const float* xr = xn + (size_t)gr * WD;
      #pragma unroll
      for (int i = 0; i < 3; ++i)
        #pragma unroll
        for (int j = 0; j < 8; ++j)
          v[i][j] = xr[(size_t)j * HWD + i * 64 + lane];
    } else {
      #pragma unroll
      for (int i = 0; i < 3; ++i)
        #pragma unroll
        for (int j = 0; j < 8; ++j) v[i][j] = 0.f;
    }
  };
  auto stage_write = [&](int gr, const float v[3][8]) {
    int s = gr & 3;
    #pragma unroll
    for (int i = 0; i < 3; ++i) {
      short8 t;
      #pragma unroll
      for (int j = 0; j < 8; ++j) t[j] = (short)f2bf(v[i][j]);
      *reinterpret_cast<short8*>(ldsb + ldso(s, 1 + i * 64 + lane, wv * 16)) = t;
    }
    if (lane < 2) {   // zero the left/right pad pixels (cols 0 and 193)
      short8 z = (short8){0,0,0,0,0,0,0,0};
      *reinterpret_cast<short8*>(ldsb + ldso(s, lane * (COLS - 1), wv * 16)) = z;
    }
  };

  // compute row r from slots (r-1,r,r+1); store AFTER the barrier (caller).
  f32x4 acc[3][2];
  auto compute_row = [&](int r) {
    int bo0[NK], bo1[NK];
    #pragma unroll
    for (int k = 0; k < NK; ++k) {
      int pix = wq * 48 + dc[k] + 1 + l15;
      bo0[k] = ldso((r + dr[k]) & 3, pix, g * 16);
      bo1[k] = ldso((r + dr[k]) & 3, pix, g * 16 + 64);   // NOT bo0+64 (swizzle)
    }
    #pragma unroll
    for (int t = 0; t < 3; ++t) {
      acc[t][0] = (f32x4){0.f, 0.f, 0.f, 0.f};
      acc[t][1] = (f32x4){0.f, 0.f, 0.f, 0.f};
    }
    __builtin_amdgcn_s_setprio(1);
    #pragma unroll
    for (int t = 0; t < 3; ++t)
      #pragma unroll
      for (int k = 0; k < NK; ++k) {
        // +t*16*ROWB only touches bits >= 11 -> linear add is swizzle-safe
        short8 b0 = *reinterpret_cast<const short8*>(ldsb + bo0[k] + t * 16 * ROWB);
        short8 b1 = *reinterpret_cast<const short8*>(ldsb + bo1[k] + t * 16 * ROWB);
        acc[t][0] = __builtin_amdgcn_mfma_f32_16x16x32_bf16(a[0][0][k], b0, acc[t][0], 0, 0, 0);
        acc[t][1] = __builtin_amdgcn_mfma_f32_16x16x32_bf16(a[1][0][k], b0, acc[t][1], 0, 0, 0);
        acc[t][0] = __builtin_amdgcn_mfma_f32_16x16x32_bf16(a[0][1][k], b1, acc[t][0], 0, 0, 0);
        acc[t][1] = __builtin_amdgcn_mfma_f32_16x16x32_bf16(a[1][1][k], b1, acc[t][1], 0, 0, 0);
      }
    __builtin_amdgcn_s_setprio(0);
  };
  auto store_row = [&](int r) {
    size_t ob = ((size_t)(n * NOUT + o0w + 4 * g) * HD + r) * WD + wq * 48 + l15;
    #pragma unroll
    for (int t = 0; t < 3; ++t)
      #pragma unroll
      for (int ot = 0; ot < 2; ++ot)
        #pragma unroll
        for (int q = 0; q < 4; ++q)
          out[ob + (size_t)(ot * 16 + q) * HWD + t * 16] = acc[t][ot][q];
  };

  float vA[3][8], vB[3][8];

  // prologue: rows r0-1..r0+1 staged; r0+2 loads in flight (vA)
  stage_load(r0 - 1, vA); stage_write(r0 - 1, vA);
  stage_load(r0,     vA); stage_write(r0,     vA);
  stage_load(r0 + 1, vA); stage_write(r0 + 1, vA);
  stage_load(r0 + 2, vA);
  lds_barrier();

  // steady state, unrolled x2 for static vA/vB ping-pong (rule #20).
  // Order per row: issue loads(r+3) -> compute r -> stage_write(r+2) [counted
  // vmcnt: 48 younger ops outstanding] -> lgkm-only barrier -> stores r.
  #pragma unroll 1
  for (int i = 0; i < BAND / 2; ++i) {
    int r = r0 + 2 * i;
    {
      if (r + 3 <= r0 + BAND) stage_load(r + 3, vB);
      compute_row(r);
      stage_write(r + 2, vA);            // r+2 <= r0+12 always here
      lds_barrier();
      store_row(r);
    }
    {
      int r1 = r + 1;
      if (r1 + 3 <= r0 + BAND) stage_load(r1 + 3, vA);
      compute_row(r1);
      if (r1 + 2 <= r0 + BAND) stage_write(r1 + 2, vB);
      lds_barrier();
      store_row(r1);
    }
  }
}

extern "C" void kernel_launch(void* const* d_in, const int* in_sizes, int n_in,
                              void* d_out, int out_size, void* d_ws, size_t ws_size,
                              hipStream_t stream) {
  const float* x = (const float*)d_in[0];
  const float* w = (const float*)d_in[1];
  const int* rot = (const int*)d_in[2];
  float* out     = (float*)d_out;
  int* taps      = (int*)d_ws;

  const int nbatch = in_sizes[0] / (NCH * HWD);   // 16

  hipLaunchKernelGGL(prep_taps_k, dim3(1), dim3(1), 0, stream, rot, taps);
  hipLaunchKernelGGL(rconv_ring_k, dim3(HD / BAND, nbatch), dim3(512), 0, stream,
                     x, w, taps, out);
}